// Round 4
// baseline (373.488 us; speedup 1.0000x reference)
//
#include <hip/hip_runtime.h>
#include <hip/hip_bf16.h>
#include <hip/hip_cooperative_groups.h>

namespace cg = cooperative_groups;

#define NBH 64
#define NSEQ 2048
#define DD 128
#define EPS 1e-6f

typedef __bf16 bf16x8 __attribute__((ext_vector_type(8)));
typedef __bf16 bf16x4 __attribute__((ext_vector_type(4)));
typedef float  f32x4  __attribute__((ext_vector_type(4)));

__device__ __forceinline__ float elu1(float x) {
    // elu(x)+1 = x+1 (x>0), exp(x) (x<=0)
    return x > 0.f ? x + 1.f : __expf(x);
}

// XOR swizzle (units of 8 bf16 = 16 B slot) for [128][64] bf16 tiles: makes
// both the column-writes (d = 4c+i) and the b128 MFMA row-reads land at the
// wave64 b128 bank floor.
__device__ __forceinline__ int swz(int r) {
    return ((r >> 2) & 7) ^ ((r & 1) << 2);
}

// ---------------------------------------------------------------------------
// Fused cooperative kernel.  grid (8, 64) = (s-chunk, bh), 512 threads,
// exactly 2 blocks/CU co-resident (LDS 66.5 KB, VGPR capped 128).
//   Phase A: partial KV^T for 256-row chunk  (R2's proven kv_partial, 60 us)
//   grid.sync()
//   Phase B: 8-way partial reduce -> bf16 kvt[bh][e][d]
//   grid.sync()
//   Phase C: out = rmsnorm(Qf @ KV) for 256 Q-rows (KVT staged once,
//            two 128-row chunks, chunk-1 Q prefetched over chunk-0 compute)
// ---------------------------------------------------------------------------
struct SmemA {
    __bf16 KfT[2][128 * 64];   // [buf][d][n]  16 KB each
    __bf16 VfT[2][128 * 64];   // [buf][e][n]
    float  mloc[256];
};

__global__ __launch_bounds__(512, 4) void fused_kernel(
    const float* __restrict__ Q, const float* __restrict__ K,
    const float* __restrict__ V, const float* __restrict__ mask,
    float* __restrict__ part, __bf16* __restrict__ kvt,
    float* __restrict__ out)
{
    __shared__ union __align__(16) {
        SmemA  a;                    // phase A: 66560 B
        __bf16 kvtile[128 * 136];    // phase C: 34816 B
    } sm;

    cg::grid_group grid = cg::this_grid();

    const int s    = blockIdx.x;
    const int bh   = blockIdx.y;
    const int b    = bh >> 4;
    const int t    = threadIdx.x;
    const int lane = t & 63;
    const int w    = t >> 6;       // wave 0..7
    const int quad = lane >> 4;
    const int col  = lane & 15;
    const int n0   = s * 256;

    // ======================= Phase A: partial KV^T =======================
    {
        const int isV = t >> 8;        // K-half / V-half staging role
        const int c   = t & 31;        // d-group: d = 4c+i
        const int rg  = (t >> 5) & 7;  // rows rg*8 .. +7 within 64-row tile

        const f32x4* S4 = (const f32x4*)((isV ? V : K) + ((size_t)bh * NSEQ + n0) * DD);
        __bf16* myT = isV ? &sm.a.VfT[0][0] : &sm.a.KfT[0][0];

        f32x4 acc[8];
        #pragma unroll
        for (int nt = 0; nt < 8; ++nt) acc[nt] = (f32x4){0.f, 0.f, 0.f, 0.f};

        const int arow = w * 16 + col;
        const int aidx = arow * 64 + (swz(arow) << 3);
        int bidx[8];
        #pragma unroll
        for (int nt = 0; nt < 8; ++nt) {
            int r = nt * 16 + col;
            bidx[nt] = r * 64 + (swz(r) << 3);
        }

        f32x4 xr[8];   // staging registers (32 VGPR)

        auto load_tile = [&](int tile) {
            #pragma unroll
            for (int j = 0; j < 8; ++j)
                xr[j] = S4[(tile * 64 + rg * 8 + j) * 32 + c];
        };

        auto stage = [&](int buf, int tile) {
            float ml[8];
            #pragma unroll
            for (int j = 0; j < 8; ++j) ml[j] = sm.a.mloc[tile * 64 + rg * 8 + j];
            __bf16* dst = myT + buf * (128 * 64);
            #pragma unroll
            for (int i = 0; i < 4; ++i) {
                bf16x8 xc;
                if (!isV) {
                    #pragma unroll
                    for (int j = 0; j < 8; ++j) xc[j] = (__bf16)(elu1(xr[j][i]) * ml[j]);
                } else {
                    #pragma unroll
                    for (int j = 0; j < 8; ++j) xc[j] = (__bf16)(xr[j][i] * ml[j]);
                }
                int d = 4 * c + i;
                *(bf16x8*)&dst[d * 64 + ((rg ^ swz(d)) << 3)] = xc;
            }
        };

        auto mfma_tile = [&](int buf) {
            const __bf16* Vb = &sm.a.VfT[buf][0];
            const __bf16* Kb = &sm.a.KfT[buf][0];
            #pragma unroll
            for (int kk = 0; kk < 2; ++kk) {
                int k0 = kk * 32 + quad * 8;
                bf16x8 a = *(bf16x8*)&Vb[aidx ^ k0];
                #pragma unroll
                for (int nt = 0; nt < 8; ++nt) {
                    bf16x8 bb = *(bf16x8*)&Kb[bidx[nt] ^ k0];
                    acc[nt] = __builtin_amdgcn_mfma_f32_16x16x32_bf16(a, bb, acc[nt], 0, 0, 0);
                }
            }
        };

        if (t < 256) sm.a.mloc[t] = mask[b * NSEQ + n0 + t];
        load_tile(0);
        __syncthreads();               // mloc visible
        stage(0, 0);
        __syncthreads();               // tile 0 staged

        #pragma unroll
        for (int tile = 0; tile < 4; ++tile) {
            if (tile < 3) load_tile(tile + 1);        // prefetch in flight
            mfma_tile(tile & 1);
            if (tile < 3) {
                stage((tile + 1) & 1, tile + 1);      // waits on prefetch here
                __syncthreads();
            }
        }

        // store partial KV^T (fp32), layout [e][d]
        float* po = part + (((size_t)bh * 8 + s) << 14);
        #pragma unroll
        for (int r = 0; r < 4; ++r) {
            int e = w * 16 + quad * 4 + r;
            #pragma unroll
            for (int nt = 0; nt < 8; ++nt)
                po[e * 128 + nt * 16 + col] = acc[nt][r];
        }
    }

    grid.sync();

    // ============== Phase B: sum 8 partials -> bf16 kvt ==============
    {
        int ii = s * 2048 + t * 4;
        const float* p = part + (((size_t)bh * 8) << 14) + ii;
        f32x4 sum = (f32x4){0.f, 0.f, 0.f, 0.f};
        #pragma unroll
        for (int ps = 0; ps < 8; ++ps)
            sum += *(const f32x4*)(p + ((size_t)ps << 14));
        bf16x4 o;
        o[0] = (__bf16)sum[0]; o[1] = (__bf16)sum[1];
        o[2] = (__bf16)sum[2]; o[3] = (__bf16)sum[3];
        *(bf16x4*)&kvt[((size_t)bh << 14) + ii] = o;
    }

    grid.sync();

    // ============== Phase C: out = rmsnorm(Qf @ KV), 256 rows ==============
    {
        const int qrow = w * 16 + col;
        const f32x4* q4 = (const f32x4*)(Q + ((size_t)bh * NSEQ + n0 + qrow) * DD);

        // issue chunk-0 Q loads first (HBM latency hides under KVT staging)
        f32x4 qr0[8];
        #pragma unroll
        for (int kk = 0; kk < 4; ++kk) {
            qr0[2 * kk]     = q4[kk * 8 + quad * 2];
            qr0[2 * kk + 1] = q4[kk * 8 + quad * 2 + 1];
        }

        // stage KVT (bf16, 128x128) into padded LDS (stride 136)
        {
            const __bf16* src = kvt + ((size_t)bh << 14);
            #pragma unroll
            for (int i = 0; i < 4; ++i) {
                int idx = i * 512 + t;
                int e   = idx >> 4;
                int dd  = (idx & 15) * 8;
                *(bf16x8*)&sm.kvtile[e * 136 + dd] = *(const bf16x8*)&src[e * 128 + dd];
            }
        }
        __syncthreads();

        // convert chunk-0 A fragments (qr0 dies here, before qr1 goes live)
        bf16x8 afr[4];
        #pragma unroll
        for (int kk = 0; kk < 4; ++kk) {
            #pragma unroll
            for (int h = 0; h < 2; ++h) {
                f32x4 q = qr0[2 * kk + h];
                #pragma unroll
                for (int u = 0; u < 4; ++u)
                    afr[kk][h * 4 + u] = (__bf16)elu1(q[u]);
            }
        }

        // issue chunk-1 Q loads (rows +128) -- in flight across chunk-0 compute
        f32x4 qr1[8];
        #pragma unroll
        for (int kk = 0; kk < 4; ++kk) {
            qr1[2 * kk]     = q4[4096 + kk * 8 + quad * 2];
            qr1[2 * kk + 1] = q4[4096 + kk * 8 + quad * 2 + 1];
        }

        float* ob = out + ((size_t)bh * NSEQ + n0) * DD;

        #pragma unroll
        for (int chunk = 0; chunk < 2; ++chunk) {
            f32x4 acc[8];
            #pragma unroll
            for (int et = 0; et < 8; ++et) acc[et] = (f32x4){0.f, 0.f, 0.f, 0.f};

            #pragma unroll
            for (int kk = 0; kk < 4; ++kk) {
                int k0 = kk * 32 + quad * 8;
                #pragma unroll
                for (int et = 0; et < 8; ++et) {
                    bf16x8 bb = *(bf16x8*)&sm.kvtile[(et * 16 + col) * 136 + k0];
                    acc[et] = __builtin_amdgcn_mfma_f32_16x16x32_bf16(afr[kk], bb, acc[et], 0, 0, 0);
                }
            }

            // RMS norm per row + store.  C layout: row = quad*4+r, col = lane&15.
            #pragma unroll
            for (int r = 0; r < 4; ++r) {
                float p = 0.f;
                #pragma unroll
                for (int et = 0; et < 8; ++et) p += acc[et][r] * acc[et][r];
                p += __shfl_xor(p, 1);
                p += __shfl_xor(p, 2);
                p += __shfl_xor(p, 4);
                p += __shfl_xor(p, 8);   // sum over the 16 lanes holding this row
                float scale = rsqrtf(p * (1.0f / 128.0f) + EPS);
                int orow = chunk * 128 + w * 16 + quad * 4 + r;
                #pragma unroll
                for (int et = 0; et < 8; ++et)
                    ob[orow * DD + et * 16 + col] = acc[et][r] * scale;
            }

            if (chunk == 0) {
                #pragma unroll
                for (int kk = 0; kk < 4; ++kk) {
                    #pragma unroll
                    for (int h = 0; h < 2; ++h) {
                        f32x4 q = qr1[2 * kk + h];
                        #pragma unroll
                        for (int u = 0; u < 4; ++u)
                            afr[kk][h * 4 + u] = (__bf16)elu1(q[u]);
                    }
                }
            }
        }
    }
}

// ===========================================================================
// Fallback 3-kernel path (used only if cooperative launch is unavailable)
// ===========================================================================
__global__ __launch_bounds__(512, 4) void kv_partial_kernel(
    const float* __restrict__ K, const float* __restrict__ V,
    const float* __restrict__ mask, float* __restrict__ part)
{
    __shared__ __bf16 KfT[2][128 * 64];
    __shared__ __bf16 VfT[2][128 * 64];
    __shared__ float  mloc[256];

    const int s    = blockIdx.x;
    const int bh   = blockIdx.y;
    const int b    = bh >> 4;
    const int t    = threadIdx.x;
    const int lane = t & 63;
    const int w    = t >> 6;
    const int quad = lane >> 4;
    const int col  = lane & 15;
    const int n0   = s * 256;

    const int isV = t >> 8;
    const int c   = t & 31;
    const int rg  = (t >> 5) & 7;

    const f32x4* S4 = (const f32x4*)((isV ? V : K) + ((size_t)bh * NSEQ + n0) * DD);
    __bf16* myT = isV ? &VfT[0][0] : &KfT[0][0];

    f32x4 acc[8];
    #pragma unroll
    for (int nt = 0; nt < 8; ++nt) acc[nt] = (f32x4){0.f, 0.f, 0.f, 0.f};

    const int arow = w * 16 + col;
    const int aidx = arow * 64 + (swz(arow) << 3);
    int bidx[8];
    #pragma unroll
    for (int nt = 0; nt < 8; ++nt) {
        int r = nt * 16 + col;
        bidx[nt] = r * 64 + (swz(r) << 3);
    }

    f32x4 xr[8];

    auto load_tile = [&](int tile) {
        #pragma unroll
        for (int j = 0; j < 8; ++j)
            xr[j] = S4[(tile * 64 + rg * 8 + j) * 32 + c];
    };
    auto stage = [&](int buf, int tile) {
        float ml[8];
        #pragma unroll
        for (int j = 0; j < 8; ++j) ml[j] = mloc[tile * 64 + rg * 8 + j];
        __bf16* dst = myT + buf * (128 * 64);
        #pragma unroll
        for (int i = 0; i < 4; ++i) {
            bf16x8 xc;
            if (!isV) {
                #pragma unroll
                for (int j = 0; j < 8; ++j) xc[j] = (__bf16)(elu1(xr[j][i]) * ml[j]);
            } else {
                #pragma unroll
                for (int j = 0; j < 8; ++j) xc[j] = (__bf16)(xr[j][i] * ml[j]);
            }
            int d = 4 * c + i;
            *(bf16x8*)&dst[d * 64 + ((rg ^ swz(d)) << 3)] = xc;
        }
    };
    auto mfma_tile = [&](int buf) {
        const __bf16* Vb = &VfT[buf][0];
        const __bf16* Kb = &KfT[buf][0];
        #pragma unroll
        for (int kk = 0; kk < 2; ++kk) {
            int k0 = kk * 32 + quad * 8;
            bf16x8 a = *(bf16x8*)&Vb[aidx ^ k0];
            #pragma unroll
            for (int nt = 0; nt < 8; ++nt) {
                bf16x8 bb = *(bf16x8*)&Kb[bidx[nt] ^ k0];
                acc[nt] = __builtin_amdgcn_mfma_f32_16x16x32_bf16(a, bb, acc[nt], 0, 0, 0);
            }
        }
    };

    if (t < 256) mloc[t] = mask[b * NSEQ + n0 + t];
    load_tile(0);
    __syncthreads();
    stage(0, 0);
    __syncthreads();

    #pragma unroll
    for (int tile = 0; tile < 4; ++tile) {
        if (tile < 3) load_tile(tile + 1);
        mfma_tile(tile & 1);
        if (tile < 3) {
            stage((tile + 1) & 1, tile + 1);
            __syncthreads();
        }
    }

    float* po = part + (((size_t)bh * 8 + s) << 14);
    #pragma unroll
    for (int r = 0; r < 4; ++r) {
        int e = w * 16 + quad * 4 + r;
        #pragma unroll
        for (int nt = 0; nt < 8; ++nt)
            po[e * 128 + nt * 16 + col] = acc[nt][r];
    }
}

__global__ __launch_bounds__(256) void kv_reduce_kernel(
    const float* __restrict__ part, __bf16* __restrict__ kvt)
{
    int gid = blockIdx.x * 256 + threadIdx.x;
    int i   = gid * 4;
    int bh  = i >> 14;
    int ii  = i & 16383;
    const float* p = part + (((size_t)bh * 8) << 14) + ii;
    f32x4 sum = (f32x4){0.f, 0.f, 0.f, 0.f};
    #pragma unroll
    for (int s = 0; s < 8; ++s)
        sum += *(const f32x4*)(p + ((size_t)s << 14));
    bf16x4 o;
    o[0] = (__bf16)sum[0]; o[1] = (__bf16)sum[1];
    o[2] = (__bf16)sum[2]; o[3] = (__bf16)sum[3];
    *(bf16x4*)&kvt[i] = o;
}

__global__ __launch_bounds__(256, 4) void qkv_norm_kernel(
    const float* __restrict__ Q, const __bf16* __restrict__ kvt,
    float* __restrict__ out)
{
    __shared__ __bf16 KVT[128 * 136];

    const int bh   = blockIdx.y;
    const int row0 = blockIdx.x * 64;
    const int t    = threadIdx.x;
    const int lane = t & 63;
    const int w    = t >> 6;
    const int quad = lane >> 4;
    const int col  = lane & 15;

    const int row = row0 + w * 16 + col;
    const f32x4* q4 = (const f32x4*)(Q + ((size_t)bh * NSEQ + row) * DD);
    f32x4 qr[8];
    #pragma unroll
    for (int kk = 0; kk < 4; ++kk) {
        qr[2 * kk]     = q4[kk * 8 + quad * 2];
        qr[2 * kk + 1] = q4[kk * 8 + quad * 2 + 1];
    }

    {
        const __bf16* src = kvt + ((size_t)bh << 14);
        #pragma unroll
        for (int i = 0; i < 8; ++i) {
            int idx = i * 256 + t;
            int e   = idx >> 4;
            int dd  = (idx & 15) * 8;
            *(bf16x8*)&KVT[e * 136 + dd] = *(const bf16x8*)&src[e * 128 + dd];
        }
    }
    __syncthreads();

    bf16x8 a[4];
    #pragma unroll
    for (int kk = 0; kk < 4; ++kk) {
        #pragma unroll
        for (int h = 0; h < 2; ++h) {
            f32x4 q = qr[2 * kk + h];
            #pragma unroll
            for (int u = 0; u < 4; ++u)
                a[kk][h * 4 + u] = (__bf16)elu1(q[u]);
        }
    }

    f32x4 acc[8];
    #pragma unroll
    for (int et = 0; et < 8; ++et) acc[et] = (f32x4){0.f, 0.f, 0.f, 0.f};

    #pragma unroll
    for (int kk = 0; kk < 4; ++kk) {
        int k0 = kk * 32 + quad * 8;
        #pragma unroll
        for (int et = 0; et < 8; ++et) {
            bf16x8 bb = *(bf16x8*)&KVT[(et * 16 + col) * 136 + k0];
            acc[et] = __builtin_amdgcn_mfma_f32_16x16x32_bf16(a[kk], bb, acc[et], 0, 0, 0);
        }
    }

    float* ob = out + ((size_t)bh * NSEQ + row0) * DD;
    #pragma unroll
    for (int r = 0; r < 4; ++r) {
        float p = 0.f;
        #pragma unroll
        for (int et = 0; et < 8; ++et) p += acc[et][r] * acc[et][r];
        p += __shfl_xor(p, 1);
        p += __shfl_xor(p, 2);
        p += __shfl_xor(p, 4);
        p += __shfl_xor(p, 8);
        float scale = rsqrtf(p * (1.0f / 128.0f) + EPS);
        int orow = w * 16 + quad * 4 + r;
        #pragma unroll
        for (int et = 0; et < 8; ++et)
            ob[orow * DD + et * 16 + col] = acc[et][r] * scale;
    }
}

extern "C" void kernel_launch(void* const* d_in, const int* in_sizes, int n_in,
                              void* d_out, int out_size, void* d_ws, size_t ws_size,
                              hipStream_t stream) {
    const float* Q    = (const float*)d_in[0];
    const float* K    = (const float*)d_in[1];
    const float* V    = (const float*)d_in[2];
    const float* mask = (const float*)d_in[3];
    float* out = (float*)d_out;

    float*  part = (float*)d_ws;                                   // 32 MB
    __bf16* kvt  = (__bf16*)((char*)d_ws + (size_t)NBH * 8 * 16384 * 4);

    void* args[] = {(void*)&Q, (void*)&K, (void*)&V, (void*)&mask,
                    (void*)&part, (void*)&kvt, (void*)&out};
    hipError_t e = hipLaunchCooperativeKernel((const void*)fused_kernel,
                                              dim3(8, NBH), dim3(512),
                                              args, 0, stream);
    if (e != hipSuccess) {
        // fallback: proven 3-kernel path
        kv_partial_kernel<<<dim3(8, NBH), 512, 0, stream>>>(K, V, mask, part);
        kv_reduce_kernel<<<1024, 256, 0, stream>>>(part, kvt);
        qkv_norm_kernel<<<dim3(32, NBH), 256, 0, stream>>>(Q, kvt, out);
    }
}

// Round 5
// 242.748 us; speedup vs baseline: 1.5386x; 1.5386x over previous
//
#include <hip/hip_runtime.h>
#include <hip/hip_bf16.h>

#define NBH 64
#define NSEQ 2048
#define DD 128
#define EPS 1e-6f

typedef __bf16 bf16x8 __attribute__((ext_vector_type(8)));
typedef __bf16 bf16x4 __attribute__((ext_vector_type(4)));
typedef float  f32x4  __attribute__((ext_vector_type(4)));

__device__ __forceinline__ float elu1(float x) {
    // elu(x)+1 = x+1 (x>0), exp(x) (x<=0)
    return x > 0.f ? x + 1.f : __expf(x);
}

// XOR swizzle (units of 8 bf16 = 16 B slot) for [128][64] bf16 tiles: makes
// both the column-writes (d = 4c+i) and the b128 MFMA row-reads land at the
// wave64 b128 bank floor.
__device__ __forceinline__ int swz(int r) {
    return ((r >> 2) & 7) ^ ((r & 1) << 2);
}

// ---------------------------------------------------------------------------
// Phase 1: partial KV^T.  grid (8, 64) = (256-row chunk, bh), 512 threads.
// part[(bh*8+s)][e][d] = sum over chunk rows n of Vf[n,e]*Kf[n,d]   (fp32)
// 64-row tiles, double-buffered LDS, DEPTH-2 register prefetch: tile t's
// loads are issued ~(mfma + stage + mfma) = ~700 cyc before their vmcnt
// wait, vs depth-1's ~200 cyc (R2 measured 1.7 TB/s = MLP-capped; depth-2
// doubles outstanding bytes).  Two named prefetch arrays (xr0/xr1), all
// slot/buffer indices compile-time (dynamic-indexed reg arrays -> scratch).
// ---------------------------------------------------------------------------
__global__ __launch_bounds__(512, 4) void kv_partial_kernel(
    const float* __restrict__ K, const float* __restrict__ V,
    const float* __restrict__ mask, float* __restrict__ part)
{
    __shared__ __bf16 KfT[2][128 * 64];   // [buf][d][n]  16 KB each
    __shared__ __bf16 VfT[2][128 * 64];   // [buf][e][n]
    __shared__ float  mloc[256];

    const int s    = blockIdx.x;
    const int bh   = blockIdx.y;
    const int b    = bh >> 4;
    const int t    = threadIdx.x;
    const int lane = t & 63;
    const int w    = t >> 6;       // wave 0..7
    const int quad = lane >> 4;
    const int col  = lane & 15;
    const int n0   = s * 256;

    const int isV = t >> 8;        // K-half / V-half staging role
    const int c   = t & 31;        // d-group: d = 4c+i
    const int rg  = (t >> 5) & 7;  // rows rg*8 .. +7 within 64-row tile

    const f32x4* S4 = (const f32x4*)((isV ? V : K) + ((size_t)bh * NSEQ + n0) * DD);
    __bf16* myT = isV ? &VfT[0][0] : &KfT[0][0];

    f32x4 acc[8];
    #pragma unroll
    for (int nt = 0; nt < 8; ++nt) acc[nt] = (f32x4){0.f, 0.f, 0.f, 0.f};

    const int arow = w * 16 + col;
    const int aidx = arow * 64 + (swz(arow) << 3);
    int bidx[8];
    #pragma unroll
    for (int nt = 0; nt < 8; ++nt) {
        int r = nt * 16 + col;
        bidx[nt] = r * 64 + (swz(r) << 3);
    }

    f32x4 xr0[8], xr1[8];   // depth-2 prefetch slots (32 VGPR each)

    auto load_tile = [&](f32x4 (&xr)[8], int tile) {
        #pragma unroll
        for (int j = 0; j < 8; ++j)
            xr[j] = S4[(tile * 64 + rg * 8 + j) * 32 + c];
    };

    auto stage = [&](f32x4 (&xr)[8], __bf16* dst, int tile) {
        float ml[8];
        #pragma unroll
        for (int j = 0; j < 8; ++j) ml[j] = mloc[tile * 64 + rg * 8 + j];
        #pragma unroll
        for (int i = 0; i < 4; ++i) {
            bf16x8 xc;
            if (!isV) {
                #pragma unroll
                for (int j = 0; j < 8; ++j) xc[j] = (__bf16)(elu1(xr[j][i]) * ml[j]);
            } else {
                #pragma unroll
                for (int j = 0; j < 8; ++j) xc[j] = (__bf16)(xr[j][i] * ml[j]);
            }
            int d = 4 * c + i;
            *(bf16x8*)&dst[d * 64 + ((rg ^ swz(d)) << 3)] = xc;
        }
    };

    auto mfma_tile = [&](const __bf16* Vb, const __bf16* Kb) {
        #pragma unroll
        for (int kk = 0; kk < 2; ++kk) {
            int k0 = kk * 32 + quad * 8;
            bf16x8 a = *(bf16x8*)&Vb[aidx ^ k0];
            #pragma unroll
            for (int nt = 0; nt < 8; ++nt) {
                bf16x8 bb = *(bf16x8*)&Kb[bidx[nt] ^ k0];
                acc[nt] = __builtin_amdgcn_mfma_f32_16x16x32_bf16(a, bb, acc[nt], 0, 0, 0);
            }
        }
    };

    __bf16* buf0 = myT;                  // this thread's staging dest, buf 0
    __bf16* buf1 = myT + 128 * 64;       // buf 1

    if (t < 256) mloc[t] = mask[b * NSEQ + n0 + t];
    load_tile(xr0, 0);                   // 8 dwordx4 in flight
    load_tile(xr1, 1);                   // 16 in flight
    __syncthreads();                     // mloc visible
    stage(xr0, buf0, 0);                 // vmcnt(8): slot-1 stays in flight
    __syncthreads();                     // tile 0 staged

    // tile 0
    load_tile(xr0, 2);                   // refill slot 0 (16 in flight again)
    mfma_tile(&VfT[0][0], &KfT[0][0]);
    __syncthreads();
    stage(xr1, buf1, 1);                 // vmcnt(8)
    __syncthreads();
    // tile 1
    load_tile(xr1, 3);
    mfma_tile(&VfT[1][0], &KfT[1][0]);
    __syncthreads();
    stage(xr0, buf0, 2);
    __syncthreads();
    // tile 2
    mfma_tile(&VfT[0][0], &KfT[0][0]);
    __syncthreads();
    stage(xr1, buf1, 3);
    __syncthreads();
    // tile 3
    mfma_tile(&VfT[1][0], &KfT[1][0]);

    // store partial KV^T (fp32), layout [e][d]
    float* po = part + (((size_t)bh * 8 + s) << 14);
    #pragma unroll
    for (int r = 0; r < 4; ++r) {
        int e = w * 16 + quad * 4 + r;
        #pragma unroll
        for (int nt = 0; nt < 8; ++nt)
            po[e * 128 + nt * 16 + col] = acc[nt][r];
    }
}

// ---------------------------------------------------------------------------
// Phase 2: sum 8 partials -> bf16 KVT[bh][e][d].  262144 threads, 4 elems ea.
// ---------------------------------------------------------------------------
__global__ __launch_bounds__(256) void kv_reduce_kernel(
    const float* __restrict__ part, __bf16* __restrict__ kvt)
{
    int gid = blockIdx.x * 256 + threadIdx.x;   // 0..262143
    int i   = gid * 4;
    int bh  = i >> 14;
    int ii  = i & 16383;
    const float* p = part + (((size_t)bh * 8) << 14) + ii;
    f32x4 sum = (f32x4){0.f, 0.f, 0.f, 0.f};
    #pragma unroll
    for (int s = 0; s < 8; ++s)
        sum += *(const f32x4*)(p + ((size_t)s << 14));
    bf16x4 o;
    o[0] = (__bf16)sum[0]; o[1] = (__bf16)sum[1];
    o[2] = (__bf16)sum[2]; o[3] = (__bf16)sum[3];
    *(bf16x4*)&kvt[i] = o;
}

// ---------------------------------------------------------------------------
// Phase 3: out = rmsnorm( Qf @ KV ).  grid (32, 64) = (64-row chunk, bh),
// 256 threads.  Q straight from global to MFMA A-fragments (no Q LDS, one
// barrier, 34 KB LDS -> 4 blocks/CU).  [Proven in the 236.6 us run.]
// ---------------------------------------------------------------------------
__global__ __launch_bounds__(256, 4) void qkv_norm_kernel(
    const float* __restrict__ Q, const __bf16* __restrict__ kvt,
    float* __restrict__ out)
{
    __shared__ __bf16 KVT[128 * 136];

    const int bh   = blockIdx.y;
    const int row0 = blockIdx.x * 64;
    const int t    = threadIdx.x;
    const int lane = t & 63;
    const int w    = t >> 6;     // wave 0..3 -> rows [w*16, +16)
    const int quad = lane >> 4;
    const int col  = lane & 15;

    // issue Q loads first (HBM, longest latency): lane owns one row, reads
    // its quad's 8-float slices for all 4 k-steps.
    const int row = row0 + w * 16 + col;
    const f32x4* q4 = (const f32x4*)(Q + ((size_t)bh * NSEQ + row) * DD);
    f32x4 qr[8];
    #pragma unroll
    for (int kk = 0; kk < 4; ++kk) {
        qr[2 * kk]     = q4[kk * 8 + quad * 2];
        qr[2 * kk + 1] = q4[kk * 8 + quad * 2 + 1];
    }

    // stage KVT (bf16, 128x128) into padded LDS (stride 136)
    {
        const __bf16* src = kvt + ((size_t)bh << 14);
        #pragma unroll
        for (int i = 0; i < 8; ++i) {
            int idx = i * 256 + t;
            int e   = idx >> 4;
            int dd  = (idx & 15) * 8;
            *(bf16x8*)&KVT[e * 136 + dd] = *(const bf16x8*)&src[e * 128 + dd];
        }
    }
    __syncthreads();

    // elu + convert Q fragments in-register
    bf16x8 a[4];
    #pragma unroll
    for (int kk = 0; kk < 4; ++kk) {
        #pragma unroll
        for (int h = 0; h < 2; ++h) {
            f32x4 q = qr[2 * kk + h];
            #pragma unroll
            for (int u = 0; u < 4; ++u)
                a[kk][h * 4 + u] = (__bf16)elu1(q[u]);
        }
    }

    f32x4 acc[8];
    #pragma unroll
    for (int et = 0; et < 8; ++et) acc[et] = (f32x4){0.f, 0.f, 0.f, 0.f};

    #pragma unroll
    for (int kk = 0; kk < 4; ++kk) {
        int k0 = kk * 32 + quad * 8;
        #pragma unroll
        for (int et = 0; et < 8; ++et) {
            bf16x8 bb = *(bf16x8*)&KVT[(et * 16 + col) * 136 + k0];
            acc[et] = __builtin_amdgcn_mfma_f32_16x16x32_bf16(a[kk], bb, acc[et], 0, 0, 0);
        }
    }

    // RMS norm per row + store.  C layout: row = quad*4+reg, col = lane&15.
    float* ob = out + ((size_t)bh * NSEQ + row0) * DD;
    #pragma unroll
    for (int r = 0; r < 4; ++r) {
        float p = 0.f;
        #pragma unroll
        for (int et = 0; et < 8; ++et) p += acc[et][r] * acc[et][r];
        p += __shfl_xor(p, 1);
        p += __shfl_xor(p, 2);
        p += __shfl_xor(p, 4);
        p += __shfl_xor(p, 8);   // sum over the 16 lanes holding this row
        float scale = rsqrtf(p * (1.0f / 128.0f) + EPS);
        int orow = w * 16 + quad * 4 + r;
        #pragma unroll
        for (int et = 0; et < 8; ++et)
            ob[orow * DD + et * 16 + col] = acc[et][r] * scale;
    }
}

extern "C" void kernel_launch(void* const* d_in, const int* in_sizes, int n_in,
                              void* d_out, int out_size, void* d_ws, size_t ws_size,
                              hipStream_t stream) {
    const float* Q    = (const float*)d_in[0];
    const float* K    = (const float*)d_in[1];
    const float* V    = (const float*)d_in[2];
    const float* mask = (const float*)d_in[3];
    float* out = (float*)d_out;

    float*  part = (float*)d_ws;                                   // 32 MB
    __bf16* kvt  = (__bf16*)((char*)d_ws + (size_t)NBH * 8 * 16384 * 4);

    kv_partial_kernel<<<dim3(8, NBH), 512, 0, stream>>>(K, V, mask, part);
    kv_reduce_kernel<<<1024, 256, 0, stream>>>(part, kvt);
    qkv_norm_kernel<<<dim3(32, NBH), 256, 0, stream>>>(Q, kvt, out);
}

// Round 6
// 237.316 us; speedup vs baseline: 1.5738x; 1.0229x over previous
//
#include <hip/hip_runtime.h>
#include <hip/hip_bf16.h>

#define NBH 64
#define NSEQ 2048
#define DD 128
#define EPS 1e-6f

typedef __bf16 bf16x8 __attribute__((ext_vector_type(8)));
typedef __bf16 bf16x4 __attribute__((ext_vector_type(4)));
typedef float  f32x4  __attribute__((ext_vector_type(4)));

__device__ __forceinline__ float elu1(float x) {
    // elu(x)+1 = x+1 (x>0), exp(x) (x<=0)
    return x > 0.f ? x + 1.f : __expf(x);
}

// XOR swizzle (units of 8 bf16 = 16 B slot) for [128][64] bf16 tiles: makes
// both the column-writes (d = 4c+i) and the b128 MFMA row-reads land at the
// wave64 b128 bank floor.
__device__ __forceinline__ int swz(int r) {
    return ((r >> 2) & 7) ^ ((r & 1) << 2);
}

// ---------------------------------------------------------------------------
// Phase 1: partial KV^T.  grid (8, 64) = (256-row chunk, bh), 512 threads.
// part[(bh*8+s)][e][d] = sum over chunk rows n of Vf[n,e]*Kf[n,d]   (fp32)
// 64-row tiles, double-buffered LDS, depth-2 register prefetch.
//
// launch_bounds NOTE (R5 post-mortem): with 512-thread blocks the 2nd arg
// empirically maps to ~blocks/CU, not waves/EU: arg=4 capped VGPR at 64
// (R0/R2/R5 all report 60-64 + scratch spill), arg=6 capped at 40 (R3).
// The 64-reg cap forced the compiler to sink global loads into the staging
// loop -> serial ~900-cyc HBM latency chains -> 1.7 TB/s.  arg=2 lifts the
// cap to >=128 (LDS already limits residency to 2 blocks/CU, so occupancy
// is unchanged); depth-2 prefetch (16 dwordx4 in flight/thread) now fits.
// ---------------------------------------------------------------------------
__global__ __launch_bounds__(512, 2) void kv_partial_kernel(
    const float* __restrict__ K, const float* __restrict__ V,
    const float* __restrict__ mask, float* __restrict__ part)
{
    __shared__ __bf16 KfT[2][128 * 64];   // [buf][d][n]  16 KB each
    __shared__ __bf16 VfT[2][128 * 64];   // [buf][e][n]
    __shared__ float  mloc[256];

    const int s    = blockIdx.x;
    const int bh   = blockIdx.y;
    const int b    = bh >> 4;
    const int t    = threadIdx.x;
    const int lane = t & 63;
    const int w    = t >> 6;       // wave 0..7
    const int quad = lane >> 4;
    const int col  = lane & 15;
    const int n0   = s * 256;

    const int isV = t >> 8;        // K-half / V-half staging role
    const int c   = t & 31;        // d-group: d = 4c+i
    const int rg  = (t >> 5) & 7;  // rows rg*8 .. +7 within 64-row tile

    const f32x4* S4 = (const f32x4*)((isV ? V : K) + ((size_t)bh * NSEQ + n0) * DD);
    __bf16* myT = isV ? &VfT[0][0] : &KfT[0][0];

    f32x4 acc[8];
    #pragma unroll
    for (int nt = 0; nt < 8; ++nt) acc[nt] = (f32x4){0.f, 0.f, 0.f, 0.f};

    const int arow = w * 16 + col;
    const int aidx = arow * 64 + (swz(arow) << 3);
    int bidx[8];
    #pragma unroll
    for (int nt = 0; nt < 8; ++nt) {
        int r = nt * 16 + col;
        bidx[nt] = r * 64 + (swz(r) << 3);
    }

    f32x4 xr0[8], xr1[8];   // depth-2 prefetch slots (32 VGPR each)

    auto load_tile = [&](f32x4 (&xr)[8], int tile) {
        #pragma unroll
        for (int j = 0; j < 8; ++j)
            xr[j] = S4[(tile * 64 + rg * 8 + j) * 32 + c];
    };

    auto stage = [&](f32x4 (&xr)[8], __bf16* dst, int tile) {
        float ml[8];
        #pragma unroll
        for (int j = 0; j < 8; ++j) ml[j] = mloc[tile * 64 + rg * 8 + j];
        #pragma unroll
        for (int i = 0; i < 4; ++i) {
            bf16x8 xc;
            if (!isV) {
                #pragma unroll
                for (int j = 0; j < 8; ++j) xc[j] = (__bf16)(elu1(xr[j][i]) * ml[j]);
            } else {
                #pragma unroll
                for (int j = 0; j < 8; ++j) xc[j] = (__bf16)(xr[j][i] * ml[j]);
            }
            int d = 4 * c + i;
            *(bf16x8*)&dst[d * 64 + ((rg ^ swz(d)) << 3)] = xc;
        }
    };

    auto mfma_tile = [&](const __bf16* Vb, const __bf16* Kb) {
        #pragma unroll
        for (int kk = 0; kk < 2; ++kk) {
            int k0 = kk * 32 + quad * 8;
            bf16x8 a = *(bf16x8*)&Vb[aidx ^ k0];
            #pragma unroll
            for (int nt = 0; nt < 8; ++nt) {
                bf16x8 bb = *(bf16x8*)&Kb[bidx[nt] ^ k0];
                acc[nt] = __builtin_amdgcn_mfma_f32_16x16x32_bf16(a, bb, acc[nt], 0, 0, 0);
            }
        }
    };

    __bf16* buf0 = myT;                  // this thread's staging dest, buf 0
    __bf16* buf1 = myT + 128 * 64;       // buf 1

    if (t < 256) mloc[t] = mask[b * NSEQ + n0 + t];
    load_tile(xr0, 0);                   // 8 dwordx4 in flight
    load_tile(xr1, 1);                   // 16 in flight
    __syncthreads();                     // mloc visible
    stage(xr0, buf0, 0);                 // waits only on slot-0 loads
    __syncthreads();                     // tile 0 staged

    // tile 0
    load_tile(xr0, 2);                   // refill slot 0 (16 in flight again)
    mfma_tile(&VfT[0][0], &KfT[0][0]);
    __syncthreads();
    stage(xr1, buf1, 1);
    __syncthreads();
    // tile 1
    load_tile(xr1, 3);
    mfma_tile(&VfT[1][0], &KfT[1][0]);
    __syncthreads();
    stage(xr0, buf0, 2);
    __syncthreads();
    // tile 2
    mfma_tile(&VfT[0][0], &KfT[0][0]);
    __syncthreads();
    stage(xr1, buf1, 3);
    __syncthreads();
    // tile 3
    mfma_tile(&VfT[1][0], &KfT[1][0]);

    // store partial KV^T (fp32), layout [e][d]
    float* po = part + (((size_t)bh * 8 + s) << 14);
    #pragma unroll
    for (int r = 0; r < 4; ++r) {
        int e = w * 16 + quad * 4 + r;
        #pragma unroll
        for (int nt = 0; nt < 8; ++nt)
            po[e * 128 + nt * 16 + col] = acc[nt][r];
    }
}

// ---------------------------------------------------------------------------
// Phase 2: sum 8 partials -> bf16 KVT[bh][e][d].  262144 threads, 4 elems ea.
// ---------------------------------------------------------------------------
__global__ __launch_bounds__(256) void kv_reduce_kernel(
    const float* __restrict__ part, __bf16* __restrict__ kvt)
{
    int gid = blockIdx.x * 256 + threadIdx.x;   // 0..262143
    int i   = gid * 4;
    int bh  = i >> 14;
    int ii  = i & 16383;
    const float* p = part + (((size_t)bh * 8) << 14) + ii;
    f32x4 sum = (f32x4){0.f, 0.f, 0.f, 0.f};
    #pragma unroll
    for (int s = 0; s < 8; ++s)
        sum += *(const f32x4*)(p + ((size_t)s << 14));
    bf16x4 o;
    o[0] = (__bf16)sum[0]; o[1] = (__bf16)sum[1];
    o[2] = (__bf16)sum[2]; o[3] = (__bf16)sum[3];
    *(bf16x4*)&kvt[i] = o;
}

// ---------------------------------------------------------------------------
// Phase 3: out = rmsnorm( Qf @ KV ).  grid (32, 64) = (64-row chunk, bh),
// 256 threads.  Q straight from global to MFMA A-fragments (no Q LDS, one
// barrier, 34 KB LDS -> 4 blocks/CU).  [Proven in the 236.6 us run.]
// (256-thread blocks: arg 4 -> 4 waves/EU -> 128 VGPR cap under both
// interpretations; live set ~95 fits.)
// ---------------------------------------------------------------------------
__global__ __launch_bounds__(256, 4) void qkv_norm_kernel(
    const float* __restrict__ Q, const __bf16* __restrict__ kvt,
    float* __restrict__ out)
{
    __shared__ __bf16 KVT[128 * 136];

    const int bh   = blockIdx.y;
    const int row0 = blockIdx.x * 64;
    const int t    = threadIdx.x;
    const int lane = t & 63;
    const int w    = t >> 6;     // wave 0..3 -> rows [w*16, +16)
    const int quad = lane >> 4;
    const int col  = lane & 15;

    // issue Q loads first (HBM, longest latency): lane owns one row, reads
    // its quad's 8-float slices for all 4 k-steps.
    const int row = row0 + w * 16 + col;
    const f32x4* q4 = (const f32x4*)(Q + ((size_t)bh * NSEQ + row) * DD);
    f32x4 qr[8];
    #pragma unroll
    for (int kk = 0; kk < 4; ++kk) {
        qr[2 * kk]     = q4[kk * 8 + quad * 2];
        qr[2 * kk + 1] = q4[kk * 8 + quad * 2 + 1];
    }

    // stage KVT (bf16, 128x128) into padded LDS (stride 136)
    {
        const __bf16* src = kvt + ((size_t)bh << 14);
        #pragma unroll
        for (int i = 0; i < 8; ++i) {
            int idx = i * 256 + t;
            int e   = idx >> 4;
            int dd  = (idx & 15) * 8;
            *(bf16x8*)&KVT[e * 136 + dd] = *(const bf16x8*)&src[e * 128 + dd];
        }
    }
    __syncthreads();

    // elu + convert Q fragments in-register
    bf16x8 a[4];
    #pragma unroll
    for (int kk = 0; kk < 4; ++kk) {
        #pragma unroll
        for (int h = 0; h < 2; ++h) {
            f32x4 q = qr[2 * kk + h];
            #pragma unroll
            for (int u = 0; u < 4; ++u)
                a[kk][h * 4 + u] = (__bf16)elu1(q[u]);
        }
    }

    f32x4 acc[8];
    #pragma unroll
    for (int et = 0; et < 8; ++et) acc[et] = (f32x4){0.f, 0.f, 0.f, 0.f};

    #pragma unroll
    for (int kk = 0; kk < 4; ++kk) {
        int k0 = kk * 32 + quad * 8;
        #pragma unroll
        for (int et = 0; et < 8; ++et) {
            bf16x8 bb = *(bf16x8*)&KVT[(et * 16 + col) * 136 + k0];
            acc[et] = __builtin_amdgcn_mfma_f32_16x16x32_bf16(a[kk], bb, acc[et], 0, 0, 0);
        }
    }

    // RMS norm per row + store.  C layout: row = quad*4+reg, col = lane&15.
    float* ob = out + ((size_t)bh * NSEQ + row0) * DD;
    #pragma unroll
    for (int r = 0; r < 4; ++r) {
        float p = 0.f;
        #pragma unroll
        for (int et = 0; et < 8; ++et) p += acc[et][r] * acc[et][r];
        p += __shfl_xor(p, 1);
        p += __shfl_xor(p, 2);
        p += __shfl_xor(p, 4);
        p += __shfl_xor(p, 8);   // sum over the 16 lanes holding this row
        float scale = rsqrtf(p * (1.0f / 128.0f) + EPS);
        int orow = w * 16 + quad * 4 + r;
        #pragma unroll
        for (int et = 0; et < 8; ++et)
            ob[orow * DD + et * 16 + col] = acc[et][r] * scale;
    }
}

extern "C" void kernel_launch(void* const* d_in, const int* in_sizes, int n_in,
                              void* d_out, int out_size, void* d_ws, size_t ws_size,
                              hipStream_t stream) {
    const float* Q    = (const float*)d_in[0];
    const float* K    = (const float*)d_in[1];
    const float* V    = (const float*)d_in[2];
    const float* mask = (const float*)d_in[3];
    float* out = (float*)d_out;

    float*  part = (float*)d_ws;                                   // 32 MB
    __bf16* kvt  = (__bf16*)((char*)d_ws + (size_t)NBH * 8 * 16384 * 4);

    kv_partial_kernel<<<dim3(8, NBH), 512, 0, stream>>>(K, V, mask, part);
    kv_reduce_kernel<<<1024, 256, 0, stream>>>(part, kvt);
    qkv_norm_kernel<<<dim3(32, NBH), 256, 0, stream>>>(Q, kvt, out);
}